// Round 9
// baseline (797.394 us; speedup 1.0000x reference)
//
#include <hip/hip_runtime.h>
#include <hip/hip_fp16.h>
#include <math.h>

// CapsNet forward. Round 9: pconv kc=6 + 3 blocks/CU (barrier drains hidden by
// co-resident blocks); decoder 4 launches (bias/act folded into staging);
// mask parallelized.

typedef __attribute__((ext_vector_type(8))) _Float16 half8;
typedef __attribute__((ext_vector_type(8))) short short8;
typedef __attribute__((ext_vector_type(4))) float floatx4;

__device__ __forceinline__ unsigned short f16bits(float v) {
    _Float16 h = (_Float16)v;
    unsigned short b;
    __builtin_memcpy(&b, &h, 2);
    return b;
}
__device__ __forceinline__ float f16back(unsigned short b) {
    _Float16 h;
    __builtin_memcpy(&h, &b, 2);
    return (float)h;
}
__device__ __forceinline__ void load_lds16(const void* g, void* l) {
    __builtin_amdgcn_global_load_lds(
        (const __attribute__((address_space(1))) unsigned int*)g,
        (__attribute__((address_space(3))) unsigned int*)l, 16, 0, 0);
}

// ---------------- conv1: x(256,1,28,28) * w(256,81) -> xpack NHWC fp16 hi/lo ----------------
__global__ __launch_bounds__(256, 2) void conv1_kernel(
    const float* __restrict__ x, const float* __restrict__ w,
    const float* __restrict__ bias, unsigned short* __restrict__ xpack)
{
    __shared__ float xs[784];
    __shared__ float wl[64 * 81];
    int t = threadIdx.x;
    int n = blockIdx.x;
    int cot = blockIdx.y;

    for (int j = t; j < 784; j += 256) xs[j] = x[n * 784 + j];
    {
        int co_s = t >> 2, k0 = (t & 3) * 21;
        const float* wsrc = w + (size_t)(cot * 64 + co_s) * 81;
        #pragma unroll
        for (int k = 0; k < 21; ++k)
            if (k0 + k < 81) wl[co_s * 81 + k0 + k] = wsrc[k0 + k];
    }
    __syncthreads();

    int co_l = t & 63, slot = t >> 6;
    int co = cot * 64 + co_l;
    float bv = bias[co];
    for (int r5 = 0; r5 < 5; ++r5) {
        int py = slot * 5 + r5;
        float acc[20];
        #pragma unroll
        for (int i = 0; i < 20; i++) acc[i] = bv;
        #pragma unroll
        for (int ky = 0; ky < 9; ++ky) {
            float xr[28];
            const float4* rowp = (const float4*)&xs[(py + ky) * 28];
            #pragma unroll
            for (int q = 0; q < 7; q++) {
                float4 v4 = rowp[q];
                xr[4*q] = v4.x; xr[4*q+1] = v4.y; xr[4*q+2] = v4.z; xr[4*q+3] = v4.w;
            }
            #pragma unroll
            for (int kx = 0; kx < 9; ++kx) {
                float wv = wl[co_l * 81 + ky * 9 + kx];
                #pragma unroll
                for (int px = 0; px < 20; ++px) acc[px] += wv * xr[px + kx];
            }
        }
        #pragma unroll
        for (int px = 0; px < 20; ++px) {
            float v = acc[px];
            unsigned short h = f16bits(v);
            unsigned short l = f16bits(v - f16back(h));
            size_t pix = (size_t)n * 400 + py * 20 + px;
            xpack[pix * 512 + co] = h;
            xpack[pix * 512 + 256 + co] = l;
        }
    }
}

// ---------------- weight repack: w[co][ci][9][9] -> frag-linear single fp16 ----------------
__global__ __launch_bounds__(256) void wpack_kernel(
    const float* __restrict__ w, unsigned short* __restrict__ wp)
{
    int tid = blockIdx.x * 256 + threadIdx.x;
    if (tid >= 648 * 16 * 64) return;
    int lane = tid & 63, g = (tid >> 6) & 15, gs = tid >> 10;
    int cb = gs & 7, kk = gs >> 3;
    int ky = kk / 9, kx = kk - ky * 9;
    int n16 = lane & 15, q = lane >> 4;
    int co = g * 16 + n16;
    unsigned short hv[8];
    #pragma unroll
    for (int j = 0; j < 8; ++j) {
        int ci = cb * 32 + q * 8 + j;
        hv[j] = f16bits(w[((size_t)co * 256 + ci) * 81 + ky * 9 + kx]);
    }
    unsigned short* dst = wp + ((size_t)gs * 16 + g) * 512 + lane * 8;
    *(short8*)dst = *(short8*)hv;
}

// ---------------- pconv GEMM: M64 x N256 x kc-split 6, 2-term fp16, BK=64 dbuf ----------------
// 72 VGPR + 64 AGPR = 136 <= 170 -> 3 blocks/CU; 864 blocks.
__global__ __launch_bounds__(256, 3) void pconv_mfma_kernel(
    const unsigned short* __restrict__ xp, const unsigned short* __restrict__ wp,
    __half* __restrict__ P6)
{
    __shared__ unsigned char lds[32768];        // 2 bufs x (2 gs x 8KB)
    int t = threadIdx.x;
    int lane = t & 63;
    int w = __builtin_amdgcn_readfirstlane(t >> 6);
    int mtile = blockIdx.x, kc = blockIdx.y;    // 144 mtiles of 64 rows, 6 kc of 108 gs
    int m16 = lane & 15, q = lane >> 4;

    unsigned int asrc[2];
    #pragma unroll
    for (int j = 0; j < 2; ++j) {
        int r = w * 16 + j * 8 + (lane >> 3);
        int m = mtile * 64 + r;
        int n = m / 36, pos = m - n * 36;
        int oy = pos / 6, ox = pos - oy * 6;
        int pixbase = n * 400 + oy * 40 + ox * 2;
        int pp = (lane & 7) ^ (lane >> 3);       // XOR swizzle
        int partoff = (pp < 4) ? pp * 16 : 512 + (pp - 4) * 16;
        asrc[j] = (unsigned int)(pixbase * 1024 + partoff);
    }
    const char* xb = (const char*)xp;
    const char* wb = (const char*)wp;

    floatx4 acc[4][4];
    #pragma unroll
    for (int a = 0; a < 4; ++a)
        #pragma unroll
        for (int b = 0; b < 4; ++b) acc[a][b] = (floatx4){0.f, 0.f, 0.f, 0.f};

    int slot_hi = (q ^ (m16 & 7)) * 16;
    int slot_lo = slot_hi ^ 64;

    auto stageP = [&](int p, int buf) {
        #pragma unroll
        for (int e = 0; e < 2; ++e) {
            int s = 2 * p + e; if (s > 107) s = 107;
            int gs = kc * 108 + s;
            int kk = gs >> 3, cb = gs & 7;
            int ky = kk / 9, kx = kk - ky * 9;
            unsigned int delta = (unsigned int)((ky * 20 + kx) * 1024 + cb * 64);
            #pragma unroll
            for (int j = 0; j < 2; ++j)
                load_lds16(xb + asrc[j] + delta,
                           (void*)(lds + buf * 16384 + e * 8192 + w * 2048 + j * 1024));
        }
    };
    auto loadB = [&](int s, half8* B) {
        if (s > 107) s = 107;
        int gs = kc * 108 + s;
        #pragma unroll
        for (int c = 0; c < 4; ++c)
            B[c] = *(const half8*)(wb + ((size_t)gs * 16 + (w * 4 + c)) * 1024 + lane * 16);
    };
    auto compute = [&](int buf, int e, half8* B) {
        #pragma unroll
        for (int ms = 0; ms < 4; ++ms) {
            const char* base = (const char*)lds + buf * 16384 + e * 8192 + (ms * 16 + m16) * 128;
            half8 Ah = *(const half8*)(base + slot_hi);
            half8 Al = *(const half8*)(base + slot_lo);
            #pragma unroll
            for (int c = 0; c < 4; ++c) {
                acc[ms][c] = __builtin_amdgcn_mfma_f32_16x16x32_f16(Ah, B[c], acc[ms][c], 0, 0, 0);
                acc[ms][c] = __builtin_amdgcn_mfma_f32_16x16x32_f16(Al, B[c], acc[ms][c], 0, 0, 0);
            }
        }
    };

    half8 Bcur[4], Bnext[4];
    stageP(0, 0);
    loadB(0, Bcur);
    __syncthreads();
    for (int p = 0; p < 54; ++p) {
        int buf = p & 1;
        stageP(p + 1, buf ^ 1);
        loadB(2 * p + 1, Bnext);
        compute(buf, 0, Bcur);
        loadB(2 * p + 2, Bcur);
        compute(buf, 1, Bnext);
        __syncthreads();
    }

    __half* outp = P6 + ((size_t)kc * 9216 + (size_t)mtile * 64) * 256;
    #pragma unroll
    for (int ms = 0; ms < 4; ++ms)
        #pragma unroll
        for (int r = 0; r < 4; ++r) {
            int ml = ms * 16 + q * 4 + r;
            #pragma unroll
            for (int c = 0; c < 4; ++c) {
                int co = w * 64 + c * 16 + m16;
                outp[ml * 256 + co] = __float2half(acc[ms][c][r]);
            }
        }
}

// ---------------- reduce 6 fp16 kc-partials + bias + squash over 8-dim capsules ----------------
__global__ __launch_bounds__(256) void squash_u_kernel(
    const __half* __restrict__ P6, const float* __restrict__ pb, float* __restrict__ u)
{
    int cap = blockIdx.x * 256 + threadIdx.x;
    int n = cap / 1152;
    int capl = cap - n * 1152;
    float z[8]; float n2 = 0.f;
    #pragma unroll
    for (int b = 0; b < 8; ++b) {
        int q2 = capl * 8 + b;
        int co = q2 / 36;
        int pos = q2 - co * 36;
        int m = n * 36 + pos;
        float s = 0.f;
        #pragma unroll
        for (int kc = 0; kc < 6; ++kc)
            s += __half2float(P6[((size_t)kc * 9216 + m) * 256 + co]);
        s += pb[co];
        z[b] = s; n2 += s * s;
    }
    float sc = sqrtf(n2) / (1.0f + n2);
    float4* op = (float4*)(u + (size_t)cap * 8);
    op[0] = make_float4(z[0]*sc, z[1]*sc, z[2]*sc, z[3]*sc);
    op[1] = make_float4(z[4]*sc, z[5]*sc, z[6]*sc, z[7]*sc);
}

// ---------------- s partials with fused softmax: block = 32n x ALL j x 24i ----------------
__global__ __launch_bounds__(256, 2) void s_kernel(
    const float* __restrict__ b, const float* __restrict__ u,
    const float* __restrict__ W, float* __restrict__ sbuf)
{
    __shared__ float cs[24][10];
    int t = threadIdx.x;
    int a = t & 15, nl = t >> 4;
    int nt = blockIdx.x;                 // 0..7
    int bz = blockIdx.y;                 // 0..47
    int i0 = bz * 24;
    int n0 = nt * 32 + nl * 2;

    if (t < 24) {
        int i = i0 + t;
        float e[10], m = -1e30f;
        #pragma unroll
        for (int j = 0; j < 10; j++) { e[j] = b[i * 10 + j]; m = fmaxf(m, e[j]); }
        float sum = 0.f;
        #pragma unroll
        for (int j = 0; j < 10; j++) { e[j] = expf(e[j] - m); sum += e[j]; }
        float inv = 1.f / sum;
        #pragma unroll
        for (int j = 0; j < 10; j++) cs[t][j] = e[j] * inv;
    }
    __syncthreads();

    float acc[2][10];
    #pragma unroll
    for (int r = 0; r < 2; ++r)
        #pragma unroll
        for (int j = 0; j < 10; ++j) acc[r][j] = 0.f;

    for (int i = i0; i < i0 + 24; ++i) {
        float4 u0[2], u1[2];
        #pragma unroll
        for (int r = 0; r < 2; ++r) {
            const float4* up = (const float4*)&u[(size_t)(n0 + r) * 9216 + (size_t)i * 8];
            u0[r] = up[0]; u1[r] = up[1];
        }
        #pragma unroll
        for (int j = 0; j < 10; ++j) {
            const float4* wpt = (const float4*)&W[(((size_t)i * 10 + j) * 16 + a) * 8];
            float4 w0 = wpt[0], w1 = wpt[1];
            float cij = cs[i - i0][j];
            #pragma unroll
            for (int r = 0; r < 2; ++r) {
                float d = w0.x*u0[r].x + w0.y*u0[r].y + w0.z*u0[r].z + w0.w*u0[r].w
                        + w1.x*u1[r].x + w1.y*u1[r].y + w1.z*u1[r].z + w1.w*u1[r].w;
                acc[r][j] += cij * d;
            }
        }
    }
    #pragma unroll
    for (int r = 0; r < 2; ++r)
        #pragma unroll
        for (int j = 0; j < 10; ++j)
            sbuf[(size_t)bz * 40960 + (((size_t)(n0 + r) * 10 + j) * 16) + a] = acc[r][j];
}

// ---------------- v = squash(sum of 48 s-partials); 160 blocks, shfl norm ----------------
__global__ __launch_bounds__(256) void squash_v_kernel(const float* __restrict__ sbuf,
                                float* __restrict__ v, float* __restrict__ vout)
{
    int t = threadIdx.x;
    int a = t & 15;
    int idx = blockIdx.x * 16 + (t >> 4);
    float s = 0.f;
    #pragma unroll
    for (int z = 0; z < 48; ++z) s += sbuf[(size_t)z * 40960 + idx * 16 + a];
    float n2 = s * s;
    n2 += __shfl_xor(n2, 1);
    n2 += __shfl_xor(n2, 2);
    n2 += __shfl_xor(n2, 4);
    n2 += __shfl_xor(n2, 8);
    float sc = sqrtf(n2) / (1.0f + n2);
    float y = s * sc;
    v[idx * 16 + a] = y;
    if (vout) vout[idx * 16 + a] = y;
}

// ---------------- b[i,j] update, i-tile of 4 per block ----------------
__global__ __launch_bounds__(192) void bupd_kernel(
    const float* __restrict__ u, const float* __restrict__ v,
    const float* __restrict__ W, float* __restrict__ b)
{
    int i0 = blockIdx.x * 4;
    int n0 = blockIdx.y * 128;
    int t = threadIdx.x;
    if (t >= 160) return;
    int j = t >> 4, a = t & 15;
    float g4[4][8];
    #pragma unroll
    for (int g = 0; g < 4; ++g)
        #pragma unroll
        for (int k = 0; k < 8; ++k) g4[g][k] = 0.f;

    for (int n = n0; n < n0 + 128; ++n) {
        float vv = v[n * 160 + t];
        const float4* ub = (const float4*)&u[(size_t)n * 9216 + (size_t)i0 * 8];
        #pragma unroll
        for (int g = 0; g < 4; ++g) {
            float4 q0 = ub[g * 2], q1 = ub[g * 2 + 1];
            g4[g][0] += q0.x * vv; g4[g][1] += q0.y * vv; g4[g][2] += q0.z * vv; g4[g][3] += q0.w * vv;
            g4[g][4] += q1.x * vv; g4[g][5] += q1.y * vv; g4[g][6] += q1.z * vv; g4[g][7] += q1.w * vv;
        }
    }
    #pragma unroll
    for (int g = 0; g < 4; ++g) {
        int i = i0 + g;
        const float4* wpt = (const float4*)&W[(((size_t)i * 10 + j) * 16 + a) * 8];
        float4 w0 = wpt[0], w1 = wpt[1];
        float p = w0.x*g4[g][0] + w0.y*g4[g][1] + w0.z*g4[g][2] + w0.w*g4[g][3]
                + w1.x*g4[g][4] + w1.y*g4[g][5] + w1.z*g4[g][6] + w1.w*g4[g][7];
        p += __shfl_xor(p, 1);
        p += __shfl_xor(p, 2);
        p += __shfl_xor(p, 4);
        p += __shfl_xor(p, 8);
        if (a == 0) atomicAdd(&b[i * 10 + j], p);
    }
}

// ---------------- argmax(|v|) + mask -> decoder input (256,160); 16 blocks ----------------
__global__ __launch_bounds__(256) void mask_kernel(const float* __restrict__ v, float* __restrict__ out)
{
    int t = threadIdx.x;
    int a = t & 15, nl = t >> 4;
    int n = blockIdx.x * 16 + nl;
    const float* vp = &v[n * 160];
    int best = 0; float bestn2 = -1.f;
    #pragma unroll
    for (int j = 0; j < 10; ++j) {
        float y = vp[j * 16 + a];
        float n2 = y * y;
        n2 += __shfl_xor(n2, 1);
        n2 += __shfl_xor(n2, 2);
        n2 += __shfl_xor(n2, 4);
        n2 += __shfl_xor(n2, 8);
        if (n2 > bestn2) { bestn2 = n2; best = j; }   // strict > = first max
    }
    #pragma unroll
    for (int j = 0; j < 10; ++j)
        out[n * 160 + j * 16 + a] = (j == best) ? vp[j * 16 + a] : 0.f;
}

// ---------------- MLP partial (from raw X): 16n x 256o per block ----------------
template<int K, int KCH, int O>
__global__ __launch_bounds__(256, 2) void mlp_part_kernel(
    const float* __restrict__ X, const float* __restrict__ Wm,
    float* __restrict__ partial)
{
    __shared__ float XS[KCH * 16];
    int t = threadIdx.x;
    int og = t & 63, ns = t >> 6;
    int n0 = blockIdx.x * 16;
    int o = blockIdx.y * 256 + og * 4;
    int o_c = min(o, O - 4);
    int ks = blockIdx.z;
    int kc0 = ks * KCH;

    for (int idx = t; idx < KCH * 16; idx += 256) {
        int k_l = idx >> 4, n_l = idx & 15;
        XS[k_l * 16 + n_l] = X[(size_t)(n0 + n_l) * K + kc0 + k_l];
    }
    __syncthreads();

    float acc[4][4];
    #pragma unroll
    for (int r = 0; r < 4; ++r)
        #pragma unroll
        for (int q = 0; q < 4; ++q) acc[r][q] = 0.f;

    #pragma unroll 8
    for (int k = 0; k < KCH; ++k) {
        float4 wv = *(const float4*)&Wm[(size_t)(kc0 + k) * O + o_c];
        float4 xs4 = *(const float4*)&XS[k * 16 + ns * 4];
        acc[0][0] += xs4.x * wv.x; acc[0][1] += xs4.x * wv.y; acc[0][2] += xs4.x * wv.z; acc[0][3] += xs4.x * wv.w;
        acc[1][0] += xs4.y * wv.x; acc[1][1] += xs4.y * wv.y; acc[1][2] += xs4.y * wv.z; acc[1][3] += xs4.y * wv.w;
        acc[2][0] += xs4.z * wv.x; acc[2][1] += xs4.z * wv.y; acc[2][2] += xs4.z * wv.z; acc[2][3] += xs4.z * wv.w;
        acc[3][0] += xs4.w * wv.x; acc[3][1] += xs4.w * wv.y; acc[3][2] += xs4.w * wv.z; acc[3][3] += xs4.w * wv.w;
    }

    if (o < O) {
        float* pp = partial + ((size_t)ks * 256 + n0 + ns * 4) * O + o;
        #pragma unroll
        for (int r = 0; r < 4; ++r)
            *(float4*)(pp + (size_t)r * O) = make_float4(acc[r][0], acc[r][1], acc[r][2], acc[r][3]);
    }
}

// ---------------- MLP partial (X = relu(sum of PRE_KS partials + bias_prev)) ----------------
template<int K, int KCH, int O, int PRE_KS>
__global__ __launch_bounds__(256, 2) void mlp_part_pre_kernel(
    const float* __restrict__ Xpart, const float* __restrict__ bprev,
    const float* __restrict__ Wm, float* __restrict__ partial)
{
    __shared__ float XS[KCH * 16];
    int t = threadIdx.x;
    int og = t & 63, ns = t >> 6;
    int n0 = blockIdx.x * 16;
    int o = blockIdx.y * 256 + og * 4;
    int o_c = min(o, O - 4);
    int ks = blockIdx.z;
    int kc0 = ks * KCH;

    for (int idx = t; idx < KCH * 16; idx += 256) {
        int k_l = idx >> 4, n_l = idx & 15;
        float s = bprev[kc0 + k_l];
        #pragma unroll
        for (int pk = 0; pk < PRE_KS; ++pk)
            s += Xpart[((size_t)pk * 256 + n0 + n_l) * K + kc0 + k_l];
        XS[k_l * 16 + n_l] = fmaxf(s, 0.f);
    }
    __syncthreads();

    float acc[4][4];
    #pragma unroll
    for (int r = 0; r < 4; ++r)
        #pragma unroll
        for (int q = 0; q < 4; ++q) acc[r][q] = 0.f;

    #pragma unroll 8
    for (int k = 0; k < KCH; ++k) {
        float4 wv = *(const float4*)&Wm[(size_t)(kc0 + k) * O + o_c];
        float4 xs4 = *(const float4*)&XS[k * 16 + ns * 4];
        acc[0][0] += xs4.x * wv.x; acc[0][1] += xs4.x * wv.y; acc[0][2] += xs4.x * wv.z; acc[0][3] += xs4.x * wv.w;
        acc[1][0] += xs4.y * wv.x; acc[1][1] += xs4.y * wv.y; acc[1][2] += xs4.y * wv.z; acc[1][3] += xs4.y * wv.w;
        acc[2][0] += xs4.z * wv.x; acc[2][1] += xs4.z * wv.y; acc[2][2] += xs4.z * wv.z; acc[2][3] += xs4.z * wv.w;
        acc[3][0] += xs4.w * wv.x; acc[3][1] += xs4.w * wv.y; acc[3][2] += xs4.w * wv.z; acc[3][3] += xs4.w * wv.w;
    }

    if (o < O) {
        float* pp = partial + ((size_t)ks * 256 + n0 + ns * 4) * O + o;
        #pragma unroll
        for (int r = 0; r < 4; ++r)
            *(float4*)(pp + (size_t)r * O) = make_float4(acc[r][0], acc[r][1], acc[r][2], acc[r][3]);
    }
}

// ---------------- MLP reduce: out[n][o] = act(sum_ks partial + bias) ----------------
template<int KS, int O, int ACT>
__global__ __launch_bounds__(256) void mlp_reduce_kernel(
    const float* __restrict__ partial, const float* __restrict__ bias,
    float* __restrict__ out)
{
    int n = blockIdx.y;
    int o = (blockIdx.x * 256 + threadIdx.x) * 4;
    if (o >= O) return;
    float4 s = make_float4(0.f, 0.f, 0.f, 0.f);
    #pragma unroll
    for (int ks = 0; ks < KS; ++ks) {
        float4 p = *(const float4*)&partial[((size_t)ks * 256 + n) * O + o];
        s.x += p.x; s.y += p.y; s.z += p.z; s.w += p.w;
    }
    float4 bv = *(const float4*)&bias[o];
    float r[4] = {s.x + bv.x, s.y + bv.y, s.z + bv.z, s.w + bv.w};
    #pragma unroll
    for (int q = 0; q < 4; ++q)
        r[q] = (ACT == 0) ? fmaxf(r[q], 0.f) : (1.f / (1.f + expf(-r[q])));
    *(float4*)&out[(size_t)n * O + o] = make_float4(r[0], r[1], r[2], r[3]);
}

extern "C" void kernel_launch(void* const* d_in, const int* in_sizes, int n_in,
                              void* d_out, int out_size, void* d_ws, size_t ws_size,
                              hipStream_t stream)
{
    const float* x       = (const float*)d_in[0];
    const float* conv1_w = (const float*)d_in[1];
    const float* conv1_b = (const float*)d_in[2];
    const float* pconv_w = (const float*)d_in[3];
    const float* pconv_b = (const float*)d_in[4];
    const float* W_caps  = (const float*)d_in[5];
    const float* dec_w1  = (const float*)d_in[6];
    const float* dec_b1  = (const float*)d_in[7];
    const float* dec_w2  = (const float*)d_in[8];
    const float* dec_b2  = (const float*)d_in[9];
    const float* dec_w3  = (const float*)d_in[10];
    const float* dec_b3  = (const float*)d_in[11];
    float* out = (float*)d_out;

    float* ws = (float*)d_ws;
    size_t off = 0;
    auto alloc = [&](size_t nf) { float* p = ws + off; off += (nf + 63) & ~(size_t)63; return p; };
    unsigned short* xpack = (unsigned short*)alloc(26214400);  // 256*400*512 ushort
    unsigned short* wpack = (unsigned short*)alloc(2654208);   // 648*16*512 ushort
    __half* P6  = (__half*)alloc(7077888);   // 6*9216*256 fp16 partials
    float* u_in = alloc(2359296);
    float* bbuf = alloc(11520);
    float* sbuf = alloc(48 * 40960);
    float* vbuf = alloc(40960);
    float* rin  = alloc(40960);
    float* mp1  = alloc(1 * 256 * 512);
    float* mp2  = alloc(2 * 256 * 1024);
    float* mp3  = alloc(4 * 256 * 784);

    hipMemsetAsync(bbuf, 0, 11520 * sizeof(float), stream);

    wpack_kernel<<<(648 * 16 * 64 + 255) / 256, 256, 0, stream>>>(pconv_w, wpack);
    conv1_kernel<<<dim3(256, 4), 256, 0, stream>>>(x, conv1_w, conv1_b, xpack);
    pconv_mfma_kernel<<<dim3(144, 6), 256, 0, stream>>>(xpack, wpack, P6);
    squash_u_kernel<<<1152, 256, 0, stream>>>(P6, pconv_b, u_in);

    for (int r = 0; r < 4; ++r) {
        s_kernel<<<dim3(8, 48), 256, 0, stream>>>(bbuf, u_in, W_caps, sbuf);
        squash_v_kernel<<<160, 256, 0, stream>>>(sbuf, vbuf, (r == 3) ? out : nullptr);
        if (r < 3) bupd_kernel<<<dim3(288, 2), 192, 0, stream>>>(u_in, vbuf, W_caps, bbuf);
    }

    mask_kernel<<<16, 256, 0, stream>>>(vbuf, rin);

    // decoder: L1 partial (pre-bias), L2/L3 fold bias+relu into staging, final reduce+sigmoid
    mlp_part_kernel<160, 160, 512><<<dim3(16, 2, 1), 256, 0, stream>>>(rin, dec_w1, mp1);
    mlp_part_pre_kernel<512, 256, 1024, 1><<<dim3(16, 4, 2), 256, 0, stream>>>(mp1, dec_b1, dec_w2, mp2);
    mlp_part_pre_kernel<1024, 256, 784, 2><<<dim3(16, 4, 4), 256, 0, stream>>>(mp2, dec_b2, dec_w3, mp3);
    mlp_reduce_kernel<4, 784, 1><<<dim3(1, 256), 256, 0, stream>>>(mp3, dec_b3, out + 40960);
}

// Round 10
// 744.695 us; speedup vs baseline: 1.0708x; 1.0708x over previous
//
#include <hip/hip_runtime.h>
#include <hip/hip_fp16.h>
#include <math.h>

// CapsNet forward. Round 10: pconv pair-loop unrolled x2 with all VMEM (A-stage
// + both next-pair B loads) issued before compute so the pre-barrier vmcnt(0)
// drain is already satisfied; decoder reverted to r8 6-launch split.

typedef __attribute__((ext_vector_type(8))) _Float16 half8;
typedef __attribute__((ext_vector_type(8))) short short8;
typedef __attribute__((ext_vector_type(4))) float floatx4;

__device__ __forceinline__ unsigned short f16bits(float v) {
    _Float16 h = (_Float16)v;
    unsigned short b;
    __builtin_memcpy(&b, &h, 2);
    return b;
}
__device__ __forceinline__ float f16back(unsigned short b) {
    _Float16 h;
    __builtin_memcpy(&h, &b, 2);
    return (float)h;
}
__device__ __forceinline__ void load_lds16(const void* g, void* l) {
    __builtin_amdgcn_global_load_lds(
        (const __attribute__((address_space(1))) unsigned int*)g,
        (__attribute__((address_space(3))) unsigned int*)l, 16, 0, 0);
}

// ---------------- conv1: x(256,1,28,28) * w(256,81) -> xpack NHWC fp16 hi/lo ----------------
__global__ __launch_bounds__(256, 2) void conv1_kernel(
    const float* __restrict__ x, const float* __restrict__ w,
    const float* __restrict__ bias, unsigned short* __restrict__ xpack)
{
    __shared__ float xs[784];
    __shared__ float wl[64 * 81];
    int t = threadIdx.x;
    int n = blockIdx.x;
    int cot = blockIdx.y;

    for (int j = t; j < 784; j += 256) xs[j] = x[n * 784 + j];
    {
        int co_s = t >> 2, k0 = (t & 3) * 21;
        const float* wsrc = w + (size_t)(cot * 64 + co_s) * 81;
        #pragma unroll
        for (int k = 0; k < 21; ++k)
            if (k0 + k < 81) wl[co_s * 81 + k0 + k] = wsrc[k0 + k];
    }
    __syncthreads();

    int co_l = t & 63, slot = t >> 6;
    int co = cot * 64 + co_l;
    float bv = bias[co];
    for (int r5 = 0; r5 < 5; ++r5) {
        int py = slot * 5 + r5;
        float acc[20];
        #pragma unroll
        for (int i = 0; i < 20; i++) acc[i] = bv;
        #pragma unroll
        for (int ky = 0; ky < 9; ++ky) {
            float xr[28];
            const float4* rowp = (const float4*)&xs[(py + ky) * 28];
            #pragma unroll
            for (int q = 0; q < 7; q++) {
                float4 v4 = rowp[q];
                xr[4*q] = v4.x; xr[4*q+1] = v4.y; xr[4*q+2] = v4.z; xr[4*q+3] = v4.w;
            }
            #pragma unroll
            for (int kx = 0; kx < 9; ++kx) {
                float wv = wl[co_l * 81 + ky * 9 + kx];
                #pragma unroll
                for (int px = 0; px < 20; ++px) acc[px] += wv * xr[px + kx];
            }
        }
        #pragma unroll
        for (int px = 0; px < 20; ++px) {
            float v = acc[px];
            unsigned short h = f16bits(v);
            unsigned short l = f16bits(v - f16back(h));
            size_t pix = (size_t)n * 400 + py * 20 + px;
            xpack[pix * 512 + co] = h;
            xpack[pix * 512 + 256 + co] = l;
        }
    }
}

// ---------------- weight repack: w[co][ci][9][9] -> frag-linear single fp16 ----------------
__global__ __launch_bounds__(256) void wpack_kernel(
    const float* __restrict__ w, unsigned short* __restrict__ wp)
{
    int tid = blockIdx.x * 256 + threadIdx.x;
    if (tid >= 648 * 16 * 64) return;
    int lane = tid & 63, g = (tid >> 6) & 15, gs = tid >> 10;
    int cb = gs & 7, kk = gs >> 3;
    int ky = kk / 9, kx = kk - ky * 9;
    int n16 = lane & 15, q = lane >> 4;
    int co = g * 16 + n16;
    unsigned short hv[8];
    #pragma unroll
    for (int j = 0; j < 8; ++j) {
        int ci = cb * 32 + q * 8 + j;
        hv[j] = f16bits(w[((size_t)co * 256 + ci) * 81 + ky * 9 + kx]);
    }
    unsigned short* dst = wp + ((size_t)gs * 16 + g) * 512 + lane * 8;
    *(short8*)dst = *(short8*)hv;
}

// ---------------- pconv GEMM: M64 x N256 x kc-split 6, 2-term fp16 ----------------
// Pair loop unrolled x2, 4 B register sets; all VMEM issued before compute.
__global__ __launch_bounds__(256, 3) void pconv_mfma_kernel(
    const unsigned short* __restrict__ xp, const unsigned short* __restrict__ wp,
    __half* __restrict__ P6)
{
    __shared__ unsigned char lds[32768];        // 2 bufs x (2 gs x 8KB)
    int t = threadIdx.x;
    int lane = t & 63;
    int w = __builtin_amdgcn_readfirstlane(t >> 6);
    int mtile = blockIdx.x, kc = blockIdx.y;    // 144 mtiles, 6 kc of 108 gs
    int m16 = lane & 15, q = lane >> 4;

    unsigned int asrc[2];
    #pragma unroll
    for (int j = 0; j < 2; ++j) {
        int r = w * 16 + j * 8 + (lane >> 3);
        int m = mtile * 64 + r;
        int n = m / 36, pos = m - n * 36;
        int oy = pos / 6, ox = pos - oy * 6;
        int pixbase = n * 400 + oy * 40 + ox * 2;
        int pp = (lane & 7) ^ (lane >> 3);       // XOR swizzle
        int partoff = (pp < 4) ? pp * 16 : 512 + (pp - 4) * 16;
        asrc[j] = (unsigned int)(pixbase * 1024 + partoff);
    }
    const char* xb = (const char*)xp;
    const char* wb = (const char*)wp;

    floatx4 acc[4][4];
    #pragma unroll
    for (int a = 0; a < 4; ++a)
        #pragma unroll
        for (int b = 0; b < 4; ++b) acc[a][b] = (floatx4){0.f, 0.f, 0.f, 0.f};

    int slot_hi = (q ^ (m16 & 7)) * 16;
    int slot_lo = slot_hi ^ 64;

    auto stageP = [&](int p, int buf) {
        #pragma unroll
        for (int e = 0; e < 2; ++e) {
            int s = 2 * p + e; if (s > 107) s = 107;
            int gs = kc * 108 + s;
            int kk = gs >> 3, cb = gs & 7;
            int ky = kk / 9, kx = kk - ky * 9;
            unsigned int delta = (unsigned int)((ky * 20 + kx) * 1024 + cb * 64);
            #pragma unroll
            for (int j = 0; j < 2; ++j)
                load_lds16(xb + asrc[j] + delta,
                           (void*)(lds + buf * 16384 + e * 8192 + w * 2048 + j * 1024));
        }
    };
    auto loadB = [&](int s, half8* B) {
        if (s > 107) s = 107;
        int gs = kc * 108 + s;
        #pragma unroll
        for (int c = 0; c < 4; ++c)
            B[c] = *(const half8*)(wb + ((size_t)gs * 16 + (w * 4 + c)) * 1024 + lane * 16);
    };
    auto compute = [&](int buf, int e, half8* B) {
        #pragma unroll
        for (int ms = 0; ms < 4; ++ms) {
            const char* base = (const char*)lds + buf * 16384 + e * 8192 + (ms * 16 + m16) * 128;
            half8 Ah = *(const half8*)(base + slot_hi);
            half8 Al = *(const half8*)(base + slot_lo);
            #pragma unroll
            for (int c = 0; c < 4; ++c) {
                acc[ms][c] = __builtin_amdgcn_mfma_f32_16x16x32_f16(Ah, B[c], acc[ms][c], 0, 0, 0);
                acc[ms][c] = __builtin_amdgcn_mfma_f32_16x16x32_f16(Al, B[c], acc[ms][c], 0, 0, 0);
            }
        }
    };

    half8 B0[4], B1[4], B2[4], B3[4];
    stageP(0, 0);
    loadB(0, B0); loadB(1, B1);
    __syncthreads();
    for (int p = 0; p < 54; p += 2) {
        // pair p (buf 0): all VMEM first, then 64 MFMAs, then barrier
        stageP(p + 1, 1);
        loadB(2 * p + 2, B2); loadB(2 * p + 3, B3);
        compute(0, 0, B0); compute(0, 1, B1);
        __syncthreads();
        // pair p+1 (buf 1)
        stageP(p + 2, 0);
        loadB(2 * p + 4, B0); loadB(2 * p + 5, B1);
        compute(1, 0, B2); compute(1, 1, B3);
        __syncthreads();
    }

    __half* outp = P6 + ((size_t)kc * 9216 + (size_t)mtile * 64) * 256;
    #pragma unroll
    for (int ms = 0; ms < 4; ++ms)
        #pragma unroll
        for (int r = 0; r < 4; ++r) {
            int ml = ms * 16 + q * 4 + r;
            #pragma unroll
            for (int c = 0; c < 4; ++c) {
                int co = w * 64 + c * 16 + m16;
                outp[ml * 256 + co] = __float2half(acc[ms][c][r]);
            }
        }
}

// ---------------- reduce 6 fp16 kc-partials + bias + squash over 8-dim capsules ----------------
__global__ __launch_bounds__(256) void squash_u_kernel(
    const __half* __restrict__ P6, const float* __restrict__ pb, float* __restrict__ u)
{
    int cap = blockIdx.x * 256 + threadIdx.x;
    int n = cap / 1152;
    int capl = cap - n * 1152;
    float z[8]; float n2 = 0.f;
    #pragma unroll
    for (int b = 0; b < 8; ++b) {
        int q2 = capl * 8 + b;
        int co = q2 / 36;
        int pos = q2 - co * 36;
        int m = n * 36 + pos;
        float s = 0.f;
        #pragma unroll
        for (int kc = 0; kc < 6; ++kc)
            s += __half2float(P6[((size_t)kc * 9216 + m) * 256 + co]);
        s += pb[co];
        z[b] = s; n2 += s * s;
    }
    float sc = sqrtf(n2) / (1.0f + n2);
    float4* op = (float4*)(u + (size_t)cap * 8);
    op[0] = make_float4(z[0]*sc, z[1]*sc, z[2]*sc, z[3]*sc);
    op[1] = make_float4(z[4]*sc, z[5]*sc, z[6]*sc, z[7]*sc);
}

// ---------------- s partials with fused softmax: block = 32n x ALL j x 24i ----------------
__global__ __launch_bounds__(256, 2) void s_kernel(
    const float* __restrict__ b, const float* __restrict__ u,
    const float* __restrict__ W, float* __restrict__ sbuf)
{
    __shared__ float cs[24][10];
    int t = threadIdx.x;
    int a = t & 15, nl = t >> 4;
    int nt = blockIdx.x;
    int bz = blockIdx.y;
    int i0 = bz * 24;
    int n0 = nt * 32 + nl * 2;

    if (t < 24) {
        int i = i0 + t;
        float e[10], m = -1e30f;
        #pragma unroll
        for (int j = 0; j < 10; j++) { e[j] = b[i * 10 + j]; m = fmaxf(m, e[j]); }
        float sum = 0.f;
        #pragma unroll
        for (int j = 0; j < 10; j++) { e[j] = expf(e[j] - m); sum += e[j]; }
        float inv = 1.f / sum;
        #pragma unroll
        for (int j = 0; j < 10; j++) cs[t][j] = e[j] * inv;
    }
    __syncthreads();

    float acc[2][10];
    #pragma unroll
    for (int r = 0; r < 2; ++r)
        #pragma unroll
        for (int j = 0; j < 10; ++j) acc[r][j] = 0.f;

    for (int i = i0; i < i0 + 24; ++i) {
        float4 u0[2], u1[2];
        #pragma unroll
        for (int r = 0; r < 2; ++r) {
            const float4* up = (const float4*)&u[(size_t)(n0 + r) * 9216 + (size_t)i * 8];
            u0[r] = up[0]; u1[r] = up[1];
        }
        #pragma unroll
        for (int j = 0; j < 10; ++j) {
            const float4* wpt = (const float4*)&W[(((size_t)i * 10 + j) * 16 + a) * 8];
            float4 w0 = wpt[0], w1 = wpt[1];
            float cij = cs[i - i0][j];
            #pragma unroll
            for (int r = 0; r < 2; ++r) {
                float d = w0.x*u0[r].x + w0.y*u0[r].y + w0.z*u0[r].z + w0.w*u0[r].w
                        + w1.x*u1[r].x + w1.y*u1[r].y + w1.z*u1[r].z + w1.w*u1[r].w;
                acc[r][j] += cij * d;
            }
        }
    }
    #pragma unroll
    for (int r = 0; r < 2; ++r)
        #pragma unroll
        for (int j = 0; j < 10; ++j)
            sbuf[(size_t)bz * 40960 + (((size_t)(n0 + r) * 10 + j) * 16) + a] = acc[r][j];
}

// ---------------- v = squash(sum of 48 s-partials); 160 blocks, shfl norm ----------------
__global__ __launch_bounds__(256) void squash_v_kernel(const float* __restrict__ sbuf,
                                float* __restrict__ v, float* __restrict__ vout)
{
    int t = threadIdx.x;
    int a = t & 15;
    int idx = blockIdx.x * 16 + (t >> 4);
    float s = 0.f;
    #pragma unroll
    for (int z = 0; z < 48; ++z) s += sbuf[(size_t)z * 40960 + idx * 16 + a];
    float n2 = s * s;
    n2 += __shfl_xor(n2, 1);
    n2 += __shfl_xor(n2, 2);
    n2 += __shfl_xor(n2, 4);
    n2 += __shfl_xor(n2, 8);
    float sc = sqrtf(n2) / (1.0f + n2);
    float y = s * sc;
    v[idx * 16 + a] = y;
    if (vout) vout[idx * 16 + a] = y;
}

// ---------------- b[i,j] update, i-tile of 4 per block ----------------
__global__ __launch_bounds__(192) void bupd_kernel(
    const float* __restrict__ u, const float* __restrict__ v,
    const float* __restrict__ W, float* __restrict__ b)
{
    int i0 = blockIdx.x * 4;
    int n0 = blockIdx.y * 128;
    int t = threadIdx.x;
    if (t >= 160) return;
    int j = t >> 4, a = t & 15;
    float g4[4][8];
    #pragma unroll
    for (int g = 0; g < 4; ++g)
        #pragma unroll
        for (int k = 0; k < 8; ++k) g4[g][k] = 0.f;

    for (int n = n0; n < n0 + 128; ++n) {
        float vv = v[n * 160 + t];
        const float4* ub = (const float4*)&u[(size_t)n * 9216 + (size_t)i0 * 8];
        #pragma unroll
        for (int g = 0; g < 4; ++g) {
            float4 q0 = ub[g * 2], q1 = ub[g * 2 + 1];
            g4[g][0] += q0.x * vv; g4[g][1] += q0.y * vv; g4[g][2] += q0.z * vv; g4[g][3] += q0.w * vv;
            g4[g][4] += q1.x * vv; g4[g][5] += q1.y * vv; g4[g][6] += q1.z * vv; g4[g][7] += q1.w * vv;
        }
    }
    #pragma unroll
    for (int g = 0; g < 4; ++g) {
        int i = i0 + g;
        const float4* wpt = (const float4*)&W[(((size_t)i * 10 + j) * 16 + a) * 8];
        float4 w0 = wpt[0], w1 = wpt[1];
        float p = w0.x*g4[g][0] + w0.y*g4[g][1] + w0.z*g4[g][2] + w0.w*g4[g][3]
                + w1.x*g4[g][4] + w1.y*g4[g][5] + w1.z*g4[g][6] + w1.w*g4[g][7];
        p += __shfl_xor(p, 1);
        p += __shfl_xor(p, 2);
        p += __shfl_xor(p, 4);
        p += __shfl_xor(p, 8);
        if (a == 0) atomicAdd(&b[i * 10 + j], p);
    }
}

// ---------------- argmax(|v|) + mask -> decoder input (256,160); 16 blocks ----------------
__global__ __launch_bounds__(256) void mask_kernel(const float* __restrict__ v, float* __restrict__ out)
{
    int t = threadIdx.x;
    int a = t & 15, nl = t >> 4;
    int n = blockIdx.x * 16 + nl;
    const float* vp = &v[n * 160];
    int best = 0; float bestn2 = -1.f;
    #pragma unroll
    for (int j = 0; j < 10; ++j) {
        float y = vp[j * 16 + a];
        float n2 = y * y;
        n2 += __shfl_xor(n2, 1);
        n2 += __shfl_xor(n2, 2);
        n2 += __shfl_xor(n2, 4);
        n2 += __shfl_xor(n2, 8);
        if (n2 > bestn2) { bestn2 = n2; best = j; }   // strict > = first max
    }
    #pragma unroll
    for (int j = 0; j < 10; ++j)
        out[n * 160 + j * 16 + a] = (j == best) ? vp[j * 16 + a] : 0.f;
}

// ---------------- MLP partial: templated K, chunked; 16n x 256o per block ----------------
template<int K, int KCH, int O>
__global__ __launch_bounds__(256, 2) void mlp_part_kernel(
    const float* __restrict__ X, const float* __restrict__ Wm,
    float* __restrict__ partial)
{
    __shared__ float XS[KCH * 16];
    int t = threadIdx.x;
    int og = t & 63, ns = t >> 6;
    int n0 = blockIdx.x * 16;
    int o = blockIdx.y * 256 + og * 4;
    int o_c = min(o, O - 4);
    int ks = blockIdx.z;
    int kc0 = ks * KCH;

    for (int idx = t; idx < KCH * 16; idx += 256) {
        int k_l = idx >> 4, n_l = idx & 15;
        XS[k_l * 16 + n_l] = X[(size_t)(n0 + n_l) * K + kc0 + k_l];
    }
    __syncthreads();

    float acc[4][4];
    #pragma unroll
    for (int r = 0; r < 4; ++r)
        #pragma unroll
        for (int q = 0; q < 4; ++q) acc[r][q] = 0.f;

    #pragma unroll 8
    for (int k = 0; k < KCH; ++k) {
        float4 wv = *(const float4*)&Wm[(size_t)(kc0 + k) * O + o_c];
        float4 xs4 = *(const float4*)&XS[k * 16 + ns * 4];
        acc[0][0] += xs4.x * wv.x; acc[0][1] += xs4.x * wv.y; acc[0][2] += xs4.x * wv.z; acc[0][3] += xs4.x * wv.w;
        acc[1][0] += xs4.y * wv.x; acc[1][1] += xs4.y * wv.y; acc[1][2] += xs4.y * wv.z; acc[1][3] += xs4.y * wv.w;
        acc[2][0] += xs4.z * wv.x; acc[2][1] += xs4.z * wv.y; acc[2][2] += xs4.z * wv.z; acc[2][3] += xs4.z * wv.w;
        acc[3][0] += xs4.w * wv.x; acc[3][1] += xs4.w * wv.y; acc[3][2] += xs4.w * wv.z; acc[3][3] += xs4.w * wv.w;
    }

    if (o < O) {
        float* pp = partial + ((size_t)ks * 256 + n0 + ns * 4) * O + o;
        #pragma unroll
        for (int r = 0; r < 4; ++r)
            *(float4*)(pp + (size_t)r * O) = make_float4(acc[r][0], acc[r][1], acc[r][2], acc[r][3]);
    }
}

// ---------------- MLP reduce: out[n][o] = act(sum_ks partial + bias) ----------------
template<int KS, int O, int ACT>
__global__ __launch_bounds__(256) void mlp_reduce_kernel(
    const float* __restrict__ partial, const float* __restrict__ bias,
    float* __restrict__ out)
{
    int n = blockIdx.y;
    int o = (blockIdx.x * 256 + threadIdx.x) * 4;
    if (o >= O) return;
    float4 s = make_float4(0.f, 0.f, 0.f, 0.f);
    #pragma unroll
    for (int ks = 0; ks < KS; ++ks) {
        float4 p = *(const float4*)&partial[((size_t)ks * 256 + n) * O + o];
        s.x += p.x; s.y += p.y; s.z += p.z; s.w += p.w;
    }
    float4 bv = *(const float4*)&bias[o];
    float r[4] = {s.x + bv.x, s.y + bv.y, s.z + bv.z, s.w + bv.w};
    #pragma unroll
    for (int q = 0; q < 4; ++q)
        r[q] = (ACT == 0) ? fmaxf(r[q], 0.f) : (1.f / (1.f + expf(-r[q])));
    *(float4*)&out[(size_t)n * O + o] = make_float4(r[0], r[1], r[2], r[3]);
}

extern "C" void kernel_launch(void* const* d_in, const int* in_sizes, int n_in,
                              void* d_out, int out_size, void* d_ws, size_t ws_size,
                              hipStream_t stream)
{
    const float* x       = (const float*)d_in[0];
    const float* conv1_w = (const float*)d_in[1];
    const float* conv1_b = (const float*)d_in[2];
    const float* pconv_w = (const float*)d_in[3];
    const float* pconv_b = (const float*)d_in[4];
    const float* W_caps  = (const float*)d_in[5];
    const float* dec_w1  = (const float*)d_in[6];
    const float* dec_b1  = (const float*)d_in[7];
    const float* dec_w2  = (const float*)d_in[8];
    const float* dec_b2  = (const float*)d_in[9];
    const float* dec_w3  = (const float*)d_in[10];
    const float* dec_b3  = (const float*)d_in[11];
    float* out = (float*)d_out;

    float* ws = (float*)d_ws;
    size_t off = 0;
    auto alloc = [&](size_t nf) { float* p = ws + off; off += (nf + 63) & ~(size_t)63; return p; };
    unsigned short* xpack = (unsigned short*)alloc(26214400);  // 256*400*512 ushort
    unsigned short* wpack = (unsigned short*)alloc(2654208);   // 648*16*512 ushort
    __half* P6  = (__half*)alloc(7077888);   // 6*9216*256 fp16 partials
    float* u_in = alloc(2359296);
    float* bbuf = alloc(11520);
    float* sbuf = alloc(48 * 40960);
    float* vbuf = alloc(40960);
    float* rin  = alloc(40960);
    float* mpart = alloc(8 * 256 * 1024);
    float* h1   = alloc(131072);
    float* h2   = alloc(262144);

    hipMemsetAsync(bbuf, 0, 11520 * sizeof(float), stream);

    wpack_kernel<<<(648 * 16 * 64 + 255) / 256, 256, 0, stream>>>(pconv_w, wpack);
    conv1_kernel<<<dim3(256, 4), 256, 0, stream>>>(x, conv1_w, conv1_b, xpack);
    pconv_mfma_kernel<<<dim3(144, 6), 256, 0, stream>>>(xpack, wpack, P6);
    squash_u_kernel<<<1152, 256, 0, stream>>>(P6, pconv_b, u_in);

    for (int r = 0; r < 4; ++r) {
        s_kernel<<<dim3(8, 48), 256, 0, stream>>>(bbuf, u_in, W_caps, sbuf);
        squash_v_kernel<<<160, 256, 0, stream>>>(sbuf, vbuf, (r == 3) ? out : nullptr);
        if (r < 3) bupd_kernel<<<dim3(288, 2), 192, 0, stream>>>(u_in, vbuf, W_caps, bbuf);
    }

    mask_kernel<<<16, 256, 0, stream>>>(vbuf, rin);

    mlp_part_kernel<160, 80, 512><<<dim3(16, 2, 2), 256, 0, stream>>>(rin, dec_w1, mpart);
    mlp_reduce_kernel<2, 512, 0><<<dim3(1, 256), 256, 0, stream>>>(mpart, dec_b1, h1);
    mlp_part_kernel<512, 128, 1024><<<dim3(16, 4, 4), 256, 0, stream>>>(h1, dec_w2, mpart);
    mlp_reduce_kernel<4, 1024, 0><<<dim3(1, 256), 256, 0, stream>>>(mpart, dec_b2, h2);
    mlp_part_kernel<1024, 128, 784><<<dim3(16, 4, 8), 256, 0, stream>>>(h2, dec_w3, mpart);
    mlp_reduce_kernel<8, 784, 1><<<dim3(1, 256), 256, 0, stream>>>(mpart, dec_b3, out + 40960);
}